// Round 3
// baseline (725.546 us; speedup 1.0000x reference)
//
#include <hip/hip_runtime.h>
#include <hip/hip_bf16.h>
#include <cstdint>

typedef __attribute__((ext_vector_type(4))) float f32x4;
typedef __attribute__((ext_vector_type(8))) short s16x8;

__device__ inline unsigned short f2bf(float f) {
    unsigned u = __float_as_uint(f);
    u = (u + 0x7fffu + ((u >> 16) & 1u)) >> 16;   // round-to-nearest-even
    return (unsigned short)u;
}
__device__ inline float bf_lo(unsigned x) { return __uint_as_float(x << 16); }
__device__ inline float bf_hi(unsigned x) { return __uint_as_float(x & 0xffff0000u); }

// ================= K1: hist | convW (independent leaves, fused) =================
__global__ __launch_bounds__(256) void k1_prep(
    const float* __restrict__ W, unsigned short* __restrict__ Wb,
    const int* __restrict__ rows, int* __restrict__ cnt, int* __restrict__ rank,
    int nhist, int e) {
    const int tid = threadIdx.x;
    const int b = blockIdx.x;
    if (b < nhist) {
        // histogram with fused rank capture
        int i = b * 256 + tid;
        if (i < e) rank[i] = atomicAdd(&cnt[rows[i]], 1);
    } else {
        // W f32 -> bf16
        int i = (b - nhist) * 256 + tid;
        if (i < 256 * 256) Wb[i] = f2bf(W[i]);
    }
}

// ================= K2: gemm_h (+ fused a1/a2 epilogue) | scan1 ==================
// gemm: block = 4 waves, tile 32 nodes x 256 outs; wave w covers outs [w*64,w*64+64).
// Reads X f32 directly (each row consumed exactly once -> no bf16 staging pass);
// converts to bf16 fragments in-register with the same RNE rounding.
// a1/a2 computed from f32 accumulators (pre bf16 rounding) + bias.
__global__ __launch_bounds__(256) void k2_gemm_scan(
    const float* __restrict__ X, const unsigned short* __restrict__ Wb,
    const float* __restrict__ bvec, unsigned short* __restrict__ Hb,
    const float* __restrict__ wa1, const float* __restrict__ ba1,
    const float* __restrict__ wa2, const float* __restrict__ ba2,
    float* __restrict__ a1, float* __restrict__ a2,
    const int* __restrict__ cnt, int* __restrict__ off, int* __restrict__ bsum,
    int ngemm, int n) {
    __shared__ float red[2][4][32];   // gemm branch: [a1|a2][wave][node-in-tile]
    __shared__ int slds[256];         // scan branch
    const int tid = threadIdx.x;

    if ((int)blockIdx.x < ngemm) {
        const int lane = tid & 63;
        const int wave = tid >> 6;
        const int l15 = lane & 15, quad = lane >> 4;
        const int nbase = blockIdx.x * 32;
        const int obase = wave * 64;

        f32x4 acc[2][4] = {};
#pragma unroll
        for (int k = 0; k < 256; k += 32) {
            s16x8 afr[2];
#pragma unroll
            for (int mt = 0; mt < 2; ++mt) {
                const float* xp = X + (size_t)(nbase + mt * 16 + l15) * 256 + k + quad * 8;
                f32x4 x0 = *(const f32x4*)xp;
                f32x4 x1 = *(const f32x4*)(xp + 4);
                s16x8 r;
                r[0] = (short)f2bf(x0.x); r[1] = (short)f2bf(x0.y);
                r[2] = (short)f2bf(x0.z); r[3] = (short)f2bf(x0.w);
                r[4] = (short)f2bf(x1.x); r[5] = (short)f2bf(x1.y);
                r[6] = (short)f2bf(x1.z); r[7] = (short)f2bf(x1.w);
                afr[mt] = r;
            }
#pragma unroll
            for (int t = 0; t < 4; ++t) {
                s16x8 bfr = *(const s16x8*)(Wb + (size_t)(obase + t * 16 + l15) * 256 + k + quad * 8);
                acc[0][t] = __builtin_amdgcn_mfma_f32_16x16x32_bf16(afr[0], bfr, acc[0][t], 0, 0, 0);
                acc[1][t] = __builtin_amdgcn_mfma_f32_16x16x32_bf16(afr[1], bfr, acc[1][t], 0, 0, 0);
            }
        }
        float bvv[4], w1v[4], w2v[4];
#pragma unroll
        for (int t = 0; t < 4; ++t) {
            int o = obase + t * 16 + l15;
            bvv[t] = bvec[o];
            w1v[t] = wa1[o];
            w2v[t] = wa2[o];
        }
#pragma unroll
        for (int mt = 0; mt < 2; ++mt) {
#pragma unroll
            for (int r = 0; r < 4; ++r) {
                const int node = nbase + mt * 16 + quad * 4 + r;
                float h0 = acc[mt][0][r] + bvv[0];
                float h1 = acc[mt][1][r] + bvv[1];
                float h2 = acc[mt][2][r] + bvv[2];
                float h3 = acc[mt][3][r] + bvv[3];
                unsigned short* hp = Hb + (size_t)node * 256 + obase + l15;
                hp[0]  = f2bf(h0);
                hp[16] = f2bf(h1);
                hp[32] = f2bf(h2);
                hp[48] = f2bf(h3);
                float p1 = h0 * w1v[0] + h1 * w1v[1] + h2 * w1v[2] + h3 * w1v[3];
                float p2 = h0 * w2v[0] + h1 * w2v[1] + h2 * w2v[2] + h3 * w2v[3];
#pragma unroll
                for (int m = 1; m < 16; m <<= 1) {  // reduce over l15 group
                    p1 += __shfl_xor(p1, m);
                    p2 += __shfl_xor(p2, m);
                }
                if (l15 == 0) {
                    red[0][wave][mt * 16 + quad * 4 + r] = p1;
                    red[1][wave][mt * 16 + quad * 4 + r] = p2;
                }
            }
        }
        __syncthreads();
        if (tid < 32) {
            a1[nbase + tid] = red[0][0][tid] + red[0][1][tid] + red[0][2][tid] + red[0][3][tid] + ba1[0];
        } else if (tid < 64) {
            int t2 = tid - 32;
            a2[nbase + t2] = red[1][0][t2] + red[1][1][t2] + red[1][2][t2] + red[1][3][t2] + ba2[0];
        }
    } else {
        // -------- scan1: per-2048-chunk inclusive scan of cnt into off[1..] --------
        const int blk = blockIdx.x - ngemm;
        const int base = blk * 2048 + tid * 8;
        int v[8];
        int run = 0;
#pragma unroll
        for (int j = 0; j < 8; ++j) {
            int idx = base + j;
            int x = (idx < n) ? cnt[idx] : 0;
            run += x;
            v[j] = run;
        }
        slds[tid] = run;
        __syncthreads();
#pragma unroll
        for (int ofs = 1; ofs < 256; ofs <<= 1) {
            int t = (tid >= ofs) ? slds[tid - ofs] : 0;
            __syncthreads();
            slds[tid] += t;
            __syncthreads();
        }
        int pre = slds[tid] - run;
#pragma unroll
        for (int j = 0; j < 8; ++j) {
            int idx = base + j;
            if (idx < n) off[1 + idx] = v[j] + pre;
        }
        if (tid == 255) bsum[blk] = slds[255];
    }
}

// ================= scan2: wave-parallel exclusive scan of block sums ============
__global__ void scan2(int* __restrict__ bsum, int* __restrict__ off, int nb) {
    const int lane = threadIdx.x & 63;
    int run = 0;
    for (int base = 0; base < nb; base += 64) {
        int i = base + lane;
        int v = (i < nb) ? bsum[i] : 0;
        int s = v;
#pragma unroll
        for (int o = 1; o < 64; o <<= 1) {
            int t = __shfl_up(s, o);
            if (lane >= o) s += t;
        }
        if (i < nb) bsum[i] = s - v + run;   // exclusive + carry
        run += __shfl(s, 63);
    }
    if (lane == 0) off[0] = 0;
}

// ================= scatter: CSR build + fused edge score ========================
// final_off[j] = off[j] + bsum[(j-1)>>11] (j>=1), 0 for j==0; bsum is 49 ints (L1).
// Writes (col, ev) pair: moves exp(leaky(a1+a2)) off aggregate's critical path;
// the gathers/VALU hide under this kernel's random-write latency.
__global__ __launch_bounds__(256) void scatter_ev(
    const int* __restrict__ rows, const int* __restrict__ colsIn,
    const int* __restrict__ rank, const int* __restrict__ off,
    const int* __restrict__ bsum,
    const float* __restrict__ a1, const float* __restrict__ a2,
    int2* __restrict__ pairs, int e) {
    int i = blockIdx.x * 256 + threadIdx.x;
    if (i < e) {
        int r = rows[i];
        int c = colsIn[i];
        float v = a1[r] + a2[c];
        v = (v > 0.0f) ? v : 0.01f * v;
        float ev = __expf(v);
        int base = (r == 0) ? 0 : (off[r] + bsum[(r - 1) >> 11]);
        pairs[base + rank[i]] = make_int2(c, __float_as_int(ev));
    }
}

// ================= single-pass streaming aggregation ============================
// block = 256 = 4 waves, one node per wave, no LDS, no sync.
// Wave split into halves: half h processes edges i+h (i += 2); 32 lanes x dwordx4
// = one full 512 B H row per half. Pair loads are lane-uniform (HW broadcast,
// 4 pairs per 64B line) and next batch is prefetched under current row loads.
// acc/s combined across halves at the end via shfl_xor(32); scale by 1/s once.
__global__ __launch_bounds__(256) void aggregate(
    const int* __restrict__ off, const int* __restrict__ bsum,
    const int2* __restrict__ pairs,
    const unsigned short* __restrict__ Hb, float* __restrict__ out) {
    const int lane = threadIdx.x & 63;
    const int wave = threadIdx.x >> 6;
    const int q = lane & 31;
    const int half = lane >> 5;
    const int node = blockIdx.x * 4 + wave;
    const int o0 = (node == 0) ? 0 : (off[node] + bsum[(node - 1) >> 11]);
    const int o1 = off[node + 1] + bsum[node >> 11];
    const int deg = o1 - o0;

    const int2* __restrict__ pp = pairs + o0;
    const unsigned short* __restrict__ hb_q = Hb + q * 8;

    float acc[8] = {0, 0, 0, 0, 0, 0, 0, 0};
    float s = 0.0f;

    int i = 0;
    int2 p0, p1, p2, p3;
    bool have = (8 <= deg);
    if (have) {
        p0 = pp[half]; p1 = pp[2 + half]; p2 = pp[4 + half]; p3 = pp[6 + half];
    }
    while (have) {
        int2 c0 = p0, c1 = p1, c2 = p2, c3 = p3;
        int ni = i + 8;
        bool nhave = (ni + 8 <= deg);
        if (nhave) {  // prefetch next batch's pairs under this batch's row loads
            p0 = pp[ni + half]; p1 = pp[ni + 2 + half];
            p2 = pp[ni + 4 + half]; p3 = pp[ni + 6 + half];
        }
        uint4 h0 = *(const uint4*)(hb_q + (size_t)c0.x * 256);
        uint4 h1 = *(const uint4*)(hb_q + (size_t)c1.x * 256);
        uint4 h2 = *(const uint4*)(hb_q + (size_t)c2.x * 256);
        uint4 h3 = *(const uint4*)(hb_q + (size_t)c3.x * 256);
        float w0 = __int_as_float(c0.y), w1 = __int_as_float(c1.y);
        float w2 = __int_as_float(c2.y), w3 = __int_as_float(c3.y);
        s += (w0 + w1) + (w2 + w3);
        acc[0] += w0 * bf_lo(h0.x); acc[1] += w0 * bf_hi(h0.x);
        acc[2] += w0 * bf_lo(h0.y); acc[3] += w0 * bf_hi(h0.y);
        acc[4] += w0 * bf_lo(h0.z); acc[5] += w0 * bf_hi(h0.z);
        acc[6] += w0 * bf_lo(h0.w); acc[7] += w0 * bf_hi(h0.w);
        acc[0] += w1 * bf_lo(h1.x); acc[1] += w1 * bf_hi(h1.x);
        acc[2] += w1 * bf_lo(h1.y); acc[3] += w1 * bf_hi(h1.y);
        acc[4] += w1 * bf_lo(h1.z); acc[5] += w1 * bf_hi(h1.z);
        acc[6] += w1 * bf_lo(h1.w); acc[7] += w1 * bf_hi(h1.w);
        acc[0] += w2 * bf_lo(h2.x); acc[1] += w2 * bf_hi(h2.x);
        acc[2] += w2 * bf_lo(h2.y); acc[3] += w2 * bf_hi(h2.y);
        acc[4] += w2 * bf_lo(h2.z); acc[5] += w2 * bf_hi(h2.z);
        acc[6] += w2 * bf_lo(h2.w); acc[7] += w2 * bf_hi(h2.w);
        acc[0] += w3 * bf_lo(h3.x); acc[1] += w3 * bf_hi(h3.x);
        acc[2] += w3 * bf_lo(h3.y); acc[3] += w3 * bf_hi(h3.y);
        acc[4] += w3 * bf_lo(h3.z); acc[5] += w3 * bf_hi(h3.z);
        acc[6] += w3 * bf_lo(h3.w); acc[7] += w3 * bf_hi(h3.w);
        i = ni;
        have = nhave;
    }
    for (; i < deg; i += 2) {  // tail (< 8 edges)
        int ii = i + half;
        if (ii < deg) {
            int2 pv = pp[ii];
            float w = __int_as_float(pv.y);
            uint4 hv = *(const uint4*)(hb_q + (size_t)pv.x * 256);
            s += w;
            acc[0] += w * bf_lo(hv.x); acc[1] += w * bf_hi(hv.x);
            acc[2] += w * bf_lo(hv.y); acc[3] += w * bf_hi(hv.y);
            acc[4] += w * bf_lo(hv.z); acc[5] += w * bf_hi(hv.z);
            acc[6] += w * bf_lo(hv.w); acc[7] += w * bf_hi(hv.w);
        }
    }
#pragma unroll
    for (int j = 0; j < 8; ++j) acc[j] += __shfl_xor(acc[j], 32);
    s += __shfl_xor(s, 32);
    float inv = (s > 0.0f) ? 1.0f / s : 0.0f;
    if (half == 0) {
        float* op = out + (size_t)node * 256 + q * 8;
        f32x4 lo = {acc[0] * inv, acc[1] * inv, acc[2] * inv, acc[3] * inv};
        f32x4 hi = {acc[4] * inv, acc[5] * inv, acc[6] * inv, acc[7] * inv};
        *(f32x4*)op = lo;
        *(f32x4*)(op + 4) = hi;
    }
}

extern "C" void kernel_launch(void* const* d_in, const int* in_sizes, int n_in,
                              void* d_out, int out_size, void* d_ws, size_t ws_size,
                              hipStream_t stream) {
    const float* X   = (const float*)d_in[0];
    const int*   idx = (const int*)d_in[1];
    const float* W   = (const float*)d_in[2];
    const float* b   = (const float*)d_in[3];
    const float* wa1 = (const float*)d_in[4];
    const float* ba1 = (const float*)d_in[5];
    const float* wa2 = (const float*)d_in[6];
    const float* ba2 = (const float*)d_in[7];
    float* out = (float*)d_out;

    const int n = in_sizes[0] / 256;  // 100000
    const int e = in_sizes[1] / 2;    // 3200000

    char* p = (char*)d_ws;
    auto alloc = [&](size_t bytes) -> char* {
        char* r = p;
        p += (bytes + 255) & ~(size_t)255;
        return r;
    };
    unsigned short* Hb = (unsigned short*)alloc((size_t)n * 256 * 2);
    unsigned short* Wb = (unsigned short*)alloc(256 * 256 * 2);
    float* a1  = (float*)alloc((size_t)n * 4);
    float* a2  = (float*)alloc((size_t)n * 4);
    int* cnt   = (int*)alloc((size_t)n * 4);
    int* off   = (int*)alloc((size_t)(n + 1) * 4);
    int* bsum  = (int*)alloc(256 * 4);
    int* rank  = (int*)alloc((size_t)e * 4);
    int2* pairs = (int2*)alloc((size_t)e * 8);

    const int* rows   = idx;
    const int* colsIn = idx + e;

    hipMemsetAsync(cnt, 0, (size_t)n * 4, stream);

    const int nhist  = (e + 255) / 256;         // 12500
    const int nconvw = 256;
    k1_prep<<<nhist + nconvw, 256, 0, stream>>>(W, Wb, rows, cnt, rank, nhist, e);
    const int ngemm = n / 32;                   // 3125
    const int nscan = (n + 2047) / 2048;        // 49
    k2_gemm_scan<<<ngemm + nscan, 256, 0, stream>>>(X, Wb, b, Hb, wa1, ba1, wa2, ba2,
                                                     a1, a2, cnt, off, bsum, ngemm, n);
    scan2<<<1, 64, 0, stream>>>(bsum, off, nscan);
    scatter_ev<<<(e + 255) / 256, 256, 0, stream>>>(rows, colsIn, rank, off, bsum,
                                                     a1, a2, pairs, e);
    aggregate<<<n / 4, 256, 0, stream>>>(off, bsum, pairs, Hb, out);
}